// Round 8
// baseline (668.639 us; speedup 1.0000x reference)
//
#include <hip/hip_runtime.h>

#define BB   16
#define NN   4096
#define SS   1024
#define D1C  128
#define D2C  256
#define CIN  384
#define CO   128
#define MM   (BB*NN)   // 65536 rows

typedef __attribute__((ext_vector_type(8))) short short8;
typedef __attribute__((ext_vector_type(8))) unsigned short ushort8;
typedef __attribute__((ext_vector_type(4))) float f32x4;

__device__ __forceinline__ unsigned short f2bf(float f) {
  unsigned u = __builtin_bit_cast(unsigned, f);
  u += 0x7fffu + ((u >> 16) & 1u);           // RNE
  return (unsigned short)(u >> 16);
}
__device__ __forceinline__ float bf2f(unsigned short u) {
  unsigned x = ((unsigned)u) << 16;
  return __builtin_bit_cast(float, x);
}
__device__ __forceinline__ unsigned cvt_pk(float lo, float hi) {
  unsigned r;
  asm("v_cvt_pk_bf16_f32 %0, %1, %2" : "=v"(r) : "v"(lo), "v"(hi));
  return r;
}
__device__ __forceinline__ ushort8 ld8(const unsigned short* p) {
  return *(const ushort8*)p;
}

#define INS(dd, ii) { if ((dd) < d2) { if ((dd) < d1) { if ((dd) < d0) { \
  d2=d1;i2=i1; d1=d0;i1=i0; d0=(dd);i0=(ii); } else { d2=d1;i2=i1; d1=(dd);i1=(ii); } } \
  else { d2=(dd);i2=(ii); } } }

// ================= prep: zero stats + top3 + transp2 + transp1 + arrange, block-partitioned =================
__global__ __launch_bounds__(256) void prep_kernel(
    const float* __restrict__ xyz1, const float* __restrict__ xyz2,
    const float* __restrict__ p1, const float* __restrict__ p2,
    const float* __restrict__ fw, const float* __restrict__ w1, const float* __restrict__ w2,
    int* __restrict__ idx3, float* __restrict__ w3,
    uint4* __restrict__ wf0, uint4* __restrict__ wf1, uint4* __restrict__ wf2,
    unsigned short* __restrict__ p2t, unsigned short* __restrict__ p1t,
    float* __restrict__ zeroRegion) {
  __shared__ float4 sp[1032];                 // 8 octants stride 129 -> conflict-free ds_read_b128
  int blk = blockIdx.x, t = threadIdx.x;
  if (blk == 0) {                             // zero gsum/gssq x3 + counters (772 floats, padded alloc)
    for (int i = t; i < 832; i += 256) zeroRegion[i] = 0.f;
  }
  { // --- top-3 NN: 2 units (32 query points each), same batch ---
    int u = blk * 2;
    int b = u >> 7;
    const float* x2 = xyz2 + (size_t)b * SS * 3;
    for (int i = t; i < SS; i += 256) {
      float a = x2[i*3+0], c = x2[i*3+1], d = x2[i*3+2];
      sp[(i >> 7) * 129 + (i & 127)] = make_float4(-2.f*a, -2.f*c, -2.f*d, a*a + c*c + d*d);
    }
    __syncthreads();
    int nl = t >> 3, q = t & 7;
    const float4* myq = sp + q * 129;
    int ibase = q * 128;
    for (int uu = 0; uu < 2; ++uu) {
      int nb = ((u + uu) & 127) * 32;
      int n  = nb + nl;
      size_t gm = (size_t)b * NN + n;
      float px = xyz1[gm*3+0], py = xyz1[gm*3+1], pz = xyz1[gm*3+2];
      float d0 = 3.4e38f, d1 = 3.4e38f, d2 = 3.4e38f;
      int   i0 = 0, i1 = 0, i2 = 0;
      #pragma unroll 4
      for (int s = 0; s < 128; ++s) {
        float4 p = myq[s];
        float d = fmaf(px, p.x, fmaf(py, p.y, fmaf(pz, p.z, p.w)));
        int i = ibase + s;
        bool c0 = d < d0, c1 = d < d1, c2 = d < d2;
        i2 = c2 ? (c1 ? i1 : i) : i2;
        i1 = c1 ? (c0 ? i0 : i) : i1;
        i0 = c0 ? i : i0;
        d2 = __builtin_amdgcn_fmed3f(d1, d2, d);
        d1 = __builtin_amdgcn_fmed3f(d0, d1, d);
        d0 = fminf(d0, d);
      }
      #pragma unroll
      for (int msk = 1; msk <= 4; msk <<= 1) {
        float e0 = __shfl_xor(d0, msk), e1 = __shfl_xor(d1, msk), e2 = __shfl_xor(d2, msk);
        int   j0 = __shfl_xor(i0, msk), j1 = __shfl_xor(i1, msk), j2 = __shfl_xor(i2, msk);
        INS(e0, j0); INS(e1, j1); INS(e2, j2);
      }
      if (q == 0) {
        float n1 = px*px + py*py + pz*pz;
        float r0 = 1.0f/(d0 + n1 + 1e-8f), r1 = 1.0f/(d1 + n1 + 1e-8f), r2 = 1.0f/(d2 + n1 + 1e-8f);
        float inv = 1.0f/(r0 + r1 + r2);
        idx3[gm*3+0] = i0; idx3[gm*3+1] = i1; idx3[gm*3+2] = i2;
        w3  [gm*3+0] = r0*inv; w3[gm*3+1] = r1*inv; w3[gm*3+2] = r2*inv;
      }
    }
  }
  { // --- transpose points2 [b][c][s] f32 -> [b][s][c] bf16: 1 unit ---
    int b  = blk >> 6;
    int s0 = (blk & 63) * 16;
    int c  = t;
    const float* src = p2 + ((size_t)b * D2C + c) * SS + s0;
    float v[16];
    #pragma unroll
    for (int k = 0; k < 4; ++k) {
      float4 x = *(const float4*)(src + k * 4);
      v[k*4+0] = x.x; v[k*4+1] = x.y; v[k*4+2] = x.z; v[k*4+3] = x.w;
    }
    unsigned short* dst = p2t + ((size_t)b * SS + s0) * D2C + c;
    #pragma unroll
    for (int s = 0; s < 16; ++s) dst[(size_t)s * D2C] = f2bf(v[s]);
  }
  // --- transpose points1 [b][c][n] f32 -> [b][n][c] bf16: 2 units ---
  for (int uu = 0; uu < 2; ++uu) {
    int u  = blk * 2 + uu;
    int b  = u >> 7;
    int n0 = (u & 127) * 32;
    int c  = t & 127;
    int n  = n0 + (t >> 7) * 16;
    const float* src = p1 + ((size_t)b * D1C + c) * NN + n;
    float v[16];
    #pragma unroll
    for (int k = 0; k < 4; ++k) {
      float4 x = *(const float4*)(src + k * 4);
      v[k*4+0] = x.x; v[k*4+1] = x.y; v[k*4+2] = x.z; v[k*4+3] = x.w;
    }
    unsigned short* dst = p1t + ((size_t)b * NN + n) * D1C + c;
    #pragma unroll
    for (int s = 0; s < 16; ++s) dst[(size_t)s * D1C] = f2bf(v[s]);
  }
  // --- arrange weights into per-lane MFMA A-fragments: blocks 0..39 ---
  if (blk < 40) {
    int gid = blk * 256 + t;
    int oblk = gid >> 6, lane = gid & 63;
    const float* w; uint4* wf; int K; int local;
    if (oblk < 96)       { w = fw; wf = wf0; K = CIN; local = oblk; }
    else if (oblk < 128) { w = w1; wf = wf1; K = CO;  local = oblk - 96; }
    else                 { w = w2; wf = wf2; K = CO;  local = oblk - 128; }
    int id = local * 64 + lane;
    int ob = (id >> 6) & 7;
    int kt = id >> 9;
    int o = ob * 16 + (lane & 15);
    int k = kt * 32 + (lane >> 4) * 8;
    const float* src = w + (size_t)o * K + k;
    union { unsigned short us[8]; uint4 v; } pk;
    #pragma unroll
    for (int j = 0; j < 8; ++j) pk.us[j] = f2bf(src[j]);
    wf[id] = pk.v;
  }
}

// ---------------- shared GEMM epilogue: tile store + fused BN-stat reduce (last-block finalize) ----------------
__device__ __forceinline__ void gemm_epilogue(
    f32x4 acc[8], const float* __restrict__ bias,
    unsigned short* __restrict__ outb, int m0b, int wid, int cl, int g, int t,
    float* __restrict__ gsum, float* __restrict__ gssq, unsigned* __restrict__ counter,
    const float* __restrict__ gamma, const float* __restrict__ beta,
    float* __restrict__ scale, float* __restrict__ shift) {
  __shared__ unsigned short tile[64][136];    // 272B row stride, 16B-aligned
  __shared__ float sS[256], sQ[256];
  __shared__ int lastFlag;
  #pragma unroll
  for (int ob = 0; ob < 8; ++ob) {
    float4 bs = *(const float4*)(bias + ob * 16 + g * 4);
    uint2 pk;
    pk.x = cvt_pk(acc[ob][0] + bs.x, acc[ob][1] + bs.y);
    pk.y = cvt_pk(acc[ob][2] + bs.z, acc[ob][3] + bs.w);
    *(uint2*)&tile[wid * 16 + cl][ob * 16 + g * 4] = pk;
  }
  __syncthreads();
  int c = t & 127, half = t >> 7;
  float s = 0.f, q = 0.f;
  #pragma unroll
  for (int i = 0; i < 32; ++i) {
    float v = bf2f(tile[half * 32 + i][c]);
    s += v; q = fmaf(v, v, q);
  }
  sS[t] = s; sQ[t] = q;
  int m_l = t >> 2, cq = (t & 3) * 32;
  unsigned short* gdst = outb + (size_t)(m0b + m_l) * CO + cq;
  #pragma unroll
  for (int qd = 0; qd < 4; ++qd)
    *(uint4*)(gdst + qd * 8) = *(const uint4*)&tile[m_l][cq + qd * 8];
  __syncthreads();
  if (t < 128) {
    atomicAdd(&gsum[t], sS[t] + sS[t + 128]);
    atomicAdd(&gssq[t], sQ[t] + sQ[t + 128]);
  }
  __threadfence();
  __syncthreads();                            // drains the stat atomics (vmcnt) before counter bump
  if (t == 0) lastFlag = (atomicAdd(counter, 1u) == 1023u);
  __syncthreads();
  if (lastFlag && t < 128) {                  // last block: all 1024 partials are in
    __threadfence();
    float S = atomicAdd(&gsum[t], 0.f);       // coherent readback
    float Q = atomicAdd(&gssq[t], 0.f);
    const float invM = 1.0f / (float)MM;
    float mean = S * invM;
    float var  = Q * invM - mean * mean;
    float rstd = rsqrtf(var + 1e-5f);
    float sc   = gamma[t] * rstd;
    scale[t] = sc;
    shift[t] = fmaf(-mean, sc, beta[t]);
  }
}

// ---------------- GEMM1 (MFMA): C[o][m], feats from p1t + 3-NN gather of p2t ----------------
__global__ __launch_bounds__(256, 4) void gemm1_mfma(
    const unsigned short* __restrict__ p1t, const unsigned short* __restrict__ p2t,
    const int* __restrict__ idx3, const float* __restrict__ w3,
    const uint4* __restrict__ wfrag, const float* __restrict__ bias,
    unsigned short* __restrict__ outb,
    float* __restrict__ gsum, float* __restrict__ gssq, unsigned* __restrict__ counter,
    const float* __restrict__ gamma, const float* __restrict__ beta,
    float* __restrict__ scale, float* __restrict__ shift) {
  int t = threadIdx.x;
  int wid = t >> 6, lane = t & 63;
  int rawblk = blockIdx.x;
  int bid = (rawblk & 7) * 128 + (rawblk >> 3);   // XCD-chunked swizzle
  int m0b = bid * 64;
  int m0 = m0b + wid * 16;
  int b  = m0 >> 12;
  int cl = lane & 15, g = lane >> 4;
  int m  = m0 + cl;
  int i0 = idx3[(size_t)m*3+0], i1 = idx3[(size_t)m*3+1], i2 = idx3[(size_t)m*3+2];
  float wA = w3[(size_t)m*3+0], wB = w3[(size_t)m*3+1], wC = w3[(size_t)m*3+2];
  const unsigned short* r0 = p2t + ((size_t)b * SS + i0) * D2C + g * 8;
  const unsigned short* r1 = p2t + ((size_t)b * SS + i1) * D2C + g * 8;
  const unsigned short* r2 = p2t + ((size_t)b * SS + i2) * D2C + g * 8;
  const unsigned short* pr = p1t + (size_t)m * D1C + g * 8;
  ushort8 pt[4], ua[4][3];
  #pragma unroll
  for (int kt = 0; kt < 4; ++kt) pt[kt] = ld8(pr + kt * 32);
  #pragma unroll
  for (int q = 0; q < 4; ++q) {
    int c0 = q * 32;
    ua[q][0] = ld8(r0 + c0); ua[q][1] = ld8(r1 + c0); ua[q][2] = ld8(r2 + c0);
  }
  f32x4 acc[8] = {};
  #pragma unroll
  for (int kt = 0; kt < 4; ++kt) {
    short8 bv = __builtin_bit_cast(short8, pt[kt]);
    const uint4* wk = wfrag + (size_t)kt * 512 + lane;
    #pragma unroll
    for (int ob = 0; ob < 8; ++ob)
      acc[ob] = __builtin_amdgcn_mfma_f32_16x16x32_bf16(
          __builtin_bit_cast(short8, wk[ob * 64]), bv, acc[ob], 0, 0, 0);
  }
  #pragma unroll
  for (int q = 0; q < 4; ++q) {
    float f[8];
    #pragma unroll
    for (int j = 0; j < 8; ++j)
      f[j] = wA*bf2f(ua[q][0][j]) + wB*bf2f(ua[q][1][j]) + wC*bf2f(ua[q][2][j]);
    uint4 pk;
    pk.x = cvt_pk(f[0], f[1]); pk.y = cvt_pk(f[2], f[3]);
    pk.z = cvt_pk(f[4], f[5]); pk.w = cvt_pk(f[6], f[7]);
    short8 bv = __builtin_bit_cast(short8, pk);
    const uint4* wk = wfrag + (size_t)(4 + q) * 512 + lane;
    #pragma unroll
    for (int ob = 0; ob < 8; ++ob)
      acc[ob] = __builtin_amdgcn_mfma_f32_16x16x32_bf16(
          __builtin_bit_cast(short8, wk[ob * 64]), bv, acc[ob], 0, 0, 0);
  }
  __builtin_amdgcn_sched_barrier(0);   // keep batch-2 loads below (VGPR cap)
  ushort8 ub[4][3];
  #pragma unroll
  for (int q = 0; q < 4; ++q) {
    int c0 = 128 + q * 32;
    ub[q][0] = ld8(r0 + c0); ub[q][1] = ld8(r1 + c0); ub[q][2] = ld8(r2 + c0);
  }
  #pragma unroll
  for (int q = 0; q < 4; ++q) {
    float f[8];
    #pragma unroll
    for (int j = 0; j < 8; ++j)
      f[j] = wA*bf2f(ub[q][0][j]) + wB*bf2f(ub[q][1][j]) + wC*bf2f(ub[q][2][j]);
    uint4 pk;
    pk.x = cvt_pk(f[0], f[1]); pk.y = cvt_pk(f[2], f[3]);
    pk.z = cvt_pk(f[4], f[5]); pk.w = cvt_pk(f[6], f[7]);
    short8 bv = __builtin_bit_cast(short8, pk);
    const uint4* wk = wfrag + (size_t)(8 + q) * 512 + lane;
    #pragma unroll
    for (int ob = 0; ob < 8; ++ob)
      acc[ob] = __builtin_amdgcn_mfma_f32_16x16x32_bf16(
          __builtin_bit_cast(short8, wk[ob * 64]), bv, acc[ob], 0, 0, 0);
  }
  gemm_epilogue(acc, bias, outb, m0b, wid, cl, g, t,
                gsum, gssq, counter, gamma, beta, scale, shift);
}

// ---------------- GEMM2/3 (MFMA): X' = relu(bn(X[m][c])); C = W @ X' + bias ----------------
__global__ __launch_bounds__(256, 4) void gemm23_mfma(
    const unsigned short* __restrict__ inb, const float* __restrict__ scIn,
    const float* __restrict__ shIn, const uint4* __restrict__ wfrag,
    const float* __restrict__ bias, unsigned short* __restrict__ outb,
    float* __restrict__ gsum, float* __restrict__ gssq, unsigned* __restrict__ counter,
    const float* __restrict__ gamma, const float* __restrict__ beta,
    float* __restrict__ scale, float* __restrict__ shift) {
  int t = threadIdx.x;
  int wid = t >> 6, lane = t & 63;
  int rawblk = blockIdx.x;
  int bid = (rawblk & 7) * 128 + (rawblk >> 3);
  int m0b = bid * 64;
  int m0 = m0b + wid * 16;
  int cl = lane & 15, g = lane >> 4;
  int m  = m0 + cl;
  const unsigned short* src = inb + (size_t)m * CO + g * 8;
  ushort8 xv[4];
  #pragma unroll
  for (int kt = 0; kt < 4; ++kt) xv[kt] = ld8(src + kt * 32);
  f32x4 acc[8] = {};
  #pragma unroll
  for (int kt = 0; kt < 4; ++kt) {
    int kb = kt * 32 + g * 8;
    float4 sa = *(const float4*)(scIn + kb), sb = *(const float4*)(scIn + kb + 4);
    float4 ha = *(const float4*)(shIn + kb), hb = *(const float4*)(shIn + kb + 4);
    float f[8];
    f[0] = fmaxf(fmaf(bf2f(xv[kt][0]), sa.x, ha.x), 0.f);
    f[1] = fmaxf(fmaf(bf2f(xv[kt][1]), sa.y, ha.y), 0.f);
    f[2] = fmaxf(fmaf(bf2f(xv[kt][2]), sa.z, ha.z), 0.f);
    f[3] = fmaxf(fmaf(bf2f(xv[kt][3]), sa.w, ha.w), 0.f);
    f[4] = fmaxf(fmaf(bf2f(xv[kt][4]), sb.x, hb.x), 0.f);
    f[5] = fmaxf(fmaf(bf2f(xv[kt][5]), sb.y, hb.y), 0.f);
    f[6] = fmaxf(fmaf(bf2f(xv[kt][6]), sb.z, hb.z), 0.f);
    f[7] = fmaxf(fmaf(bf2f(xv[kt][7]), sb.w, hb.w), 0.f);
    uint4 pk;
    pk.x = cvt_pk(f[0], f[1]); pk.y = cvt_pk(f[2], f[3]);
    pk.z = cvt_pk(f[4], f[5]); pk.w = cvt_pk(f[6], f[7]);
    short8 bv = __builtin_bit_cast(short8, pk);
    const uint4* wk = wfrag + (size_t)kt * 512 + lane;
    #pragma unroll
    for (int ob = 0; ob < 8; ++ob)
      acc[ob] = __builtin_amdgcn_mfma_f32_16x16x32_bf16(
          __builtin_bit_cast(short8, wk[ob * 64]), bv, acc[ob], 0, 0, 0);
  }
  gemm_epilogue(acc, bias, outb, m0b, wid, cl, g, t,
                gsum, gssq, counter, gamma, beta, scale, shift);
}

// ---------------- final: out[b][o][n] = relu(bn2(h2) + relu(bn0(x))), [m][c] -> [o][n] ----------------
__global__ __launch_bounds__(256) void final_kernel(
    const unsigned short* __restrict__ bufX, const unsigned short* __restrict__ bufH2,
    const float* __restrict__ bnp, float* __restrict__ out) {
  __shared__ float yt[128][33];
  __shared__ float sb[512];
  int t = threadIdx.x;
  if (t < 128) {
    sb[t]       = bnp[t];
    sb[128 + t] = bnp[128 + t];
    sb[256 + t] = bnp[512 + t];
    sb[384 + t] = bnp[640 + t];
  }
  __syncthreads();
  int m0 = blockIdx.x * 32;
  int b  = m0 >> 12;
  int n0 = m0 & (NN - 1);
  int m_l = t >> 3;
  int cq  = (t & 7) * 16;
  size_t base = (size_t)(m0 + m_l) * CO + cq;
  ushort8 xu0 = ld8(bufX  + base), xu1 = ld8(bufX  + base + 8);
  ushort8 hu0 = ld8(bufH2 + base), hu1 = ld8(bufH2 + base + 8);
  #pragma unroll
  for (int j = 0; j < 16; ++j) {
    int c = cq + j;
    float x = bf2f(j < 8 ? xu0[j & 7] : xu1[j & 7]);
    float h = bf2f(j < 8 ? hu0[j & 7] : hu1[j & 7]);
    yt[c][m_l] = fmaxf(fmaf(h, sb[256 + c], sb[384 + c]) +
                       fmaxf(fmaf(x, sb[c], sb[128 + c]), 0.f), 0.f);
  }
  __syncthreads();
  int o  = t >> 1;
  int nh = (t & 1) * 16;
  float* dst = out + (size_t)b * CO * NN + (size_t)o * NN + n0 + nh;
  #pragma unroll
  for (int qd = 0; qd < 4; ++qd)
    *(float4*)(dst + qd * 4) = make_float4(yt[o][nh + qd*4 + 0], yt[o][nh + qd*4 + 1],
                                           yt[o][nh + qd*4 + 2], yt[o][nh + qd*4 + 3]);
}

extern "C" void kernel_launch(void* const* d_in, const int* in_sizes, int n_in,
                              void* d_out, int out_size, void* d_ws, size_t ws_size,
                              hipStream_t stream) {
  const float* xyz1    = (const float*)d_in[0];
  const float* xyz2    = (const float*)d_in[1];
  const float* points1 = (const float*)d_in[2];
  const float* points2 = (const float*)d_in[3];
  const float* fuse_w  = (const float*)d_in[4];
  const float* fuse_b  = (const float*)d_in[5];
  const float* fuse_g  = (const float*)d_in[6];
  const float* fuse_be = (const float*)d_in[7];
  const float* w1      = (const float*)d_in[8];
  const float* b1      = (const float*)d_in[9];
  const float* g1      = (const float*)d_in[10];
  const float* be1     = (const float*)d_in[11];
  const float* w2      = (const float*)d_in[12];
  const float* b2      = (const float*)d_in[13];
  const float* g2      = (const float*)d_in[14];
  const float* be2     = (const float*)d_in[15];

  char* ws = (char*)d_ws;
  size_t off = 0;
  auto alloc = [&](size_t bytes) -> void* {
    void* p = ws + off;
    off += (bytes + 255) & ~(size_t)255;
    return p;
  };
  int*            idx3  = (int*)           alloc((size_t)MM * 3 * 4);
  float*          w3    = (float*)         alloc((size_t)MM * 3 * 4);
  uint4*          wf0   = (uint4*)         alloc((size_t)96 * 64 * 16);
  uint4*          wf1   = (uint4*)         alloc((size_t)32 * 64 * 16);
  uint4*          wf2   = (uint4*)         alloc((size_t)32 * 64 * 16);
  float*          stats = (float*)         alloc(6 * 128 * 4);   // gsum0,gssq0,gsum1,gssq1,gsum2,gssq2
  unsigned*       ctr   = (unsigned*)      alloc(256);           // 3 counters (contiguous after stats)
  float*          bnp   = (float*)         alloc(6 * 128 * 4);   // scale0,shift0,scale1,shift1,scale2,shift2
  unsigned short* p2t   = (unsigned short*)alloc((size_t)BB * SS * D2C * 2);
  unsigned short* p1t   = (unsigned short*)alloc((size_t)MM * D1C * 2);
  unsigned short* bufX  = (unsigned short*)alloc((size_t)MM * CO * 2);
  unsigned short* bufH  = (unsigned short*)alloc((size_t)MM * CO * 2);
  unsigned short* bufH2 = (unsigned short*)alloc((size_t)MM * CO * 2);
  if (off > ws_size) return;

  prep_kernel<<<1024, 256, 0, stream>>>(xyz1, xyz2, points1, points2,
                                        fuse_w, w1, w2, idx3, w3, wf0, wf1, wf2,
                                        p2t, p1t, stats /* zeroes stats+ctr (832 floats) */);

  gemm1_mfma<<<1024, 256, 0, stream>>>(p1t, p2t, idx3, w3, wf0, fuse_b, bufX,
                                       stats + 0, stats + 128, ctr + 0,
                                       fuse_g, fuse_be, bnp + 0, bnp + 128);

  gemm23_mfma<<<1024, 256, 0, stream>>>(bufX, bnp + 0, bnp + 128, wf1, b1, bufH,
                                        stats + 256, stats + 384, ctr + 1,
                                        g1, be1, bnp + 256, bnp + 384);

  gemm23_mfma<<<1024, 256, 0, stream>>>(bufH, bnp + 256, bnp + 384, wf2, b2, bufH2,
                                        stats + 512, stats + 640, ctr + 2,
                                        g2, be2, bnp + 512, bnp + 640);

  final_kernel<<<MM/32, 256, 0, stream>>>(bufX, bufH2, bnp, (float*)d_out);
}